// Round 5
// baseline (537.607 us; speedup 1.0000x reference)
//
#include <hip/hip_runtime.h>

#define D 128
#define ND 100000
#define NP 50000
#define NE_DD 800000
#define NE_DP 600000
#define NE_PD 600000
#define NE_TOT 2000000

#define NTOT 250000      /* concatenated dst space: [dd:100k][pd:100k][dp:50k] */
#define NBC 490          /* coarse buckets, 512 nodes each (490*512 = 250880) */
#define NC 250880
#define CHUNKA 8192      /* edges per binning block */
#define NBLKA 245        /* ceil(2M/8192) */
#define SEGCAP 8192      /* max edges per coarse bucket (expected max ~6.6k) */

#define NBLK_D 1563      /* (ND+63)/64 */
#define NBLK_P 782       /* (NP+63)/64 */

typedef __bf16 bf16;
typedef __attribute__((ext_vector_type(8))) __bf16 bf16x8;
typedef __attribute__((ext_vector_type(4))) float f32x4;

// ---------------- workspace layout (byte offsets, 16B-aligned) -------------
#define OFF_WDD   0UL
#define OFF_WDP   32768UL
#define OFF_WPD   65536UL
#define OFF_WDRUG 98304UL
#define OFF_WPROT 163840UL
#define OFF_YDD   229376UL                      /* 100k x 128 bf16 */
#define OFF_YDP   (OFF_YDD + 25600000UL)        /* 100k x 128 bf16 */
#define OFF_YPD   (OFF_YDP + 25600000UL)        /* 50k x 128 bf16 */
#define OFF_BCNT  (OFF_YPD + 12800000UL)        /* 512 ints (hist, zeroed) */
#define OFF_GCUR  (OFF_BCNT + 2048UL)           /* 512 ints (cursors, zeroed) */
#define OFF_RP    (OFF_GCUR + 2048UL)           /* NC ints (row ptrs) */
#define OFF_PAIRS (OFF_RP + 1003520UL)          /* 2M int2 (bucket-grouped) */
#define OFF_POOL  (OFF_PAIRS + 16000000UL)      /* 2M ints (node-grouped src) */

// ---------------- prep: weights->bf16  +  zero bcnt/gcur -------------------
__global__ __launch_bounds__(256) void prep_kernel(
    const float* __restrict__ w0, const float* __restrict__ w1,
    const float* __restrict__ w2, const float* __restrict__ w3,
    const float* __restrict__ w4,
    bf16* __restrict__ o0, bf16* __restrict__ o1, bf16* __restrict__ o2,
    bf16* __restrict__ o3, bf16* __restrict__ o4,
    int* __restrict__ zb)
{
    int m = blockIdx.y;
    int i = blockIdx.x * 256 + threadIdx.x;
    if (m == 5) {
        if (i < 1024) zb[i] = 0;     /* bcnt(512) + gcur(512), contiguous */
        return;
    }
    const float* src; bf16* dst; int n;
    switch (m) {
        case 0: src = w0; dst = o0; n = D * D; break;
        case 1: src = w1; dst = o1; n = D * D; break;
        case 2: src = w2; dst = o2; n = D * D; break;
        case 3: src = w3; dst = o3; n = D * 2 * D; break;
        default: src = w4; dst = o4; n = D * 2 * D; break;
    }
    if (i < n) dst[i] = (bf16)src[i];
}

// ---------------- per-node transforms: y = relu(x @ W^T) -------------------
__device__ __forceinline__ void transform_body(
    const float* __restrict__ x, const bf16* __restrict__ W1,
    const bf16* __restrict__ W2, bf16* __restrict__ y1, bf16* __restrict__ y2,
    int M, int blk, bool two)
{
    int lane = threadIdx.x & 63;
    int wave = threadIdx.x >> 6;
    int q = lane >> 4, c = lane & 15;
    int mb = blk * 64 + wave * 16;
    int rowA = min(mb + c, M - 1);

    f32x4 acc1[8], acc2[8];
#pragma unroll
    for (int i = 0; i < 8; i++) { acc1[i] = 0; acc2[i] = 0; }

    const float* xrow = x + (long)rowA * D;
#pragma unroll
    for (int kb = 0; kb < 4; kb++) {
        int k = kb * 32 + q * 8;
        float4 f0 = *(const float4*)(xrow + k);
        float4 f1 = *(const float4*)(xrow + k + 4);
        bf16x8 a;
        a[0] = (bf16)f0.x; a[1] = (bf16)f0.y; a[2] = (bf16)f0.z; a[3] = (bf16)f0.w;
        a[4] = (bf16)f1.x; a[5] = (bf16)f1.y; a[6] = (bf16)f1.z; a[7] = (bf16)f1.w;
#pragma unroll
        for (int nt = 0; nt < 8; nt++) {
            int n = nt * 16 + c;
            bf16x8 b1 = *(const bf16x8*)(W1 + n * D + k);
            acc1[nt] = __builtin_amdgcn_mfma_f32_16x16x32_bf16(a, b1, acc1[nt], 0, 0, 0);
            if (two) {
                bf16x8 b2 = *(const bf16x8*)(W2 + n * D + k);
                acc2[nt] = __builtin_amdgcn_mfma_f32_16x16x32_bf16(a, b2, acc2[nt], 0, 0, 0);
            }
        }
    }
#pragma unroll
    for (int r = 0; r < 4; r++) {
        int row = mb + q * 4 + r;
        if (row < M) {
            bf16* p1 = y1 + (long)row * D + c;
#pragma unroll
            for (int nt = 0; nt < 8; nt++)
                p1[nt * 16] = (bf16)fmaxf(acc1[nt][r], 0.f);
            if (two) {
                bf16* p2 = y2 + (long)row * D + c;
#pragma unroll
                for (int nt = 0; nt < 8; nt++)
                    p2[nt * 16] = (bf16)fmaxf(acc2[nt][r], 0.f);
            }
        }
    }
}

// ---------------- transform + coarse histogram (independent block ranges) --
__global__ __launch_bounds__(256) void transform_hist_kernel(
    const float* __restrict__ x_drug, const float* __restrict__ x_prot,
    const bf16* __restrict__ Wdd, const bf16* __restrict__ Wdp,
    const bf16* __restrict__ Wpd,
    bf16* __restrict__ y_dd, bf16* __restrict__ y_dp, bf16* __restrict__ y_pd,
    const int* __restrict__ dd_dst, const int* __restrict__ pd_dst,
    const int* __restrict__ dp_dst, int* __restrict__ bcnt)
{
    int blk = blockIdx.x;
    if (blk < NBLK_D) {
        transform_body(x_drug, Wdd, Wdp, y_dd, y_dp, ND, blk, true);
        return;
    }
    blk -= NBLK_D;
    if (blk < NBLK_P) {
        transform_body(x_prot, Wpd, Wpd, y_pd, y_pd, NP, blk, false);
        return;
    }
    blk -= NBLK_P;
    // histogram over 490 coarse buckets, LDS-staged
    __shared__ int h[NBC];
    for (int i = threadIdx.x; i < NBC; i += 256) h[i] = 0;
    __syncthreads();
    int base = blk * CHUNKA;
    for (int it = 0; it < 32; it++) {
        int e = base + it * 256 + threadIdx.x;
        if (e < NE_TOT) {
            int didx;
            if (e < NE_DD) didx = dd_dst[e];
            else if (e < NE_DD + NE_PD) didx = ND + pd_dst[e - NE_DD];
            else didx = 2 * ND + dp_dst[e - NE_DD - NE_PD];
            atomicAdd(&h[didx >> 9], 1);
        }
    }
    __syncthreads();
    for (int i = threadIdx.x; i < NBC; i += 256)
        if (h[i]) atomicAdd(&bcnt[i], h[i]);
}

// ---------------- pass A: coarse binning (scan folded in) ------------------
__global__ __launch_bounds__(256) void binA_kernel(
    const int* __restrict__ dd_src, const int* __restrict__ dd_dst,
    const int* __restrict__ pd_src, const int* __restrict__ pd_dst,
    const int* __restrict__ dp_src, const int* __restrict__ dp_dst,
    const int* __restrict__ bcnt, int* __restrict__ gcur,
    int2* __restrict__ pairs)
{
    __shared__ int h[NBC];
    __shared__ int gb[NBC];
    __shared__ int cb[512];
    __shared__ int ps[256];
    __shared__ int2 pr[CHUNKA];
    __shared__ unsigned short rk[CHUNKA];
    int t = threadIdx.x;

    // local exclusive scan of bcnt -> cb (bucket base offsets)
    {
        int i0 = 2 * t, i1 = 2 * t + 1;
        int c0 = (i0 < NBC) ? bcnt[i0] : 0;
        int c1 = (i1 < NBC) ? bcnt[i1] : 0;
        ps[t] = c0 + c1;
        __syncthreads();
#pragma unroll
        for (int off = 1; off < 256; off <<= 1) {
            int add = (t >= off) ? ps[t - off] : 0;
            __syncthreads();
            ps[t] += add;
            __syncthreads();
        }
        int excl = ps[t] - (c0 + c1);
        cb[i0] = excl;
        cb[i1] = excl + c0;
    }
    for (int i = t; i < NBC; i += 256) h[i] = 0;
    __syncthreads();

    int base = blockIdx.x * CHUNKA;
    for (int it = 0; it < 32; it++) {
        int idx = it * 256 + t;
        int e = base + idx;
        int didx = -1, sv = 0;
        if (e < NE_TOT) {
            if (e < NE_DD) { didx = dd_dst[e]; sv = dd_src[e]; }
            else if (e < NE_DD + NE_PD) { int u = e - NE_DD; didx = ND + pd_dst[u]; sv = pd_src[u]; }
            else { int u = e - NE_DD - NE_PD; didx = 2 * ND + dp_dst[u]; sv = dp_src[u]; }
            rk[idx] = (unsigned short)atomicAdd(&h[didx >> 9], 1);
        }
        pr[idx] = make_int2(didx, sv);
    }
    __syncthreads();
    for (int b = t; b < NBC; b += 256) {
        int c = h[b];
        gb[b] = c ? (cb[b] + atomicAdd(&gcur[b], c)) : 0;
    }
    __syncthreads();
    for (int it = 0; it < 32; it++) {
        int idx = it * 256 + t;
        int2 p = pr[idx];
        if (p.x >= 0) pairs[gb[p.x >> 9] + rk[idx]] = p;
    }
}

// ---------------- pass B: per-bucket LDS counting sort -> pool + rp --------
__global__ __launch_bounds__(256) void sortB_kernel(
    const int* __restrict__ bcnt, const int2* __restrict__ pairs,
    int* __restrict__ pool, int* __restrict__ rp)
{
    __shared__ int cb[512];
    __shared__ int ps[256];
    __shared__ int h[512];
    __shared__ int excl[512];
    __shared__ int srcl[SEGCAP];
    __shared__ unsigned short ll[SEGCAP];
    __shared__ unsigned short rk[SEGCAP];
    __shared__ int outl[SEGCAP];

    int t = threadIdx.x;
    // local exclusive scan of bcnt -> cb
    {
        int i0 = 2 * t, i1 = 2 * t + 1;
        int c0 = (i0 < NBC) ? bcnt[i0] : 0;
        int c1 = (i1 < NBC) ? bcnt[i1] : 0;
        ps[t] = c0 + c1;
        __syncthreads();
#pragma unroll
        for (int off = 1; off < 256; off <<= 1) {
            int add = (t >= off) ? ps[t - off] : 0;
            __syncthreads();
            ps[t] += add;
            __syncthreads();
        }
        int excl0 = ps[t] - (c0 + c1);
        cb[i0] = excl0;
        cb[i1] = excl0 + c0;
    }
    __syncthreads();

    int b = blockIdx.x;
    int s0 = cb[b];
    int n = cb[b + 1] - s0;
    if (n > SEGCAP) n = SEGCAP;   /* safety clamp; expected max ~6.6k */
    h[t] = 0; h[t + 256] = 0;
    __syncthreads();

    for (int i = t; i < n; i += 256) {
        int2 p = pairs[s0 + i];
        int l = p.x & 511;
        srcl[i] = p.y;
        ll[i] = (unsigned short)l;
        rk[i] = (unsigned short)atomicAdd(&h[l], 1);
    }
    __syncthreads();

    // exclusive scan over h[0..511] (2 elems per thread)
    int c0 = h[2 * t], c1 = h[2 * t + 1];
    ps[t] = c0 + c1;
    __syncthreads();
#pragma unroll
    for (int off = 1; off < 256; off <<= 1) {
        int add = (t >= off) ? ps[t - off] : 0;
        __syncthreads();
        ps[t] += add;
        __syncthreads();
    }
    int pe = ps[t] - (c0 + c1);
    excl[2 * t] = pe;
    excl[2 * t + 1] = pe + c0;
    __syncthreads();

    // row pointers for this bucket's 512 node slots
    int nb = b * 512;
    rp[nb + 2 * t] = s0 + excl[2 * t];
    rp[nb + 2 * t + 1] = s0 + excl[2 * t + 1];

    // LDS scatter, then coalesced copy out
    for (int i = t; i < n; i += 256)
        outl[excl[ll[i]] + rk[i]] = srcl[i];
    __syncthreads();
    for (int i = t; i < n; i += 256)
        pool[s0 + i] = outl[i];
}

// ---------------- fused gather + node update -------------------------------
// Each wave: (1) gathers per-relation means for its 16 rows into wave-local
// LDS (row stride 136 bf16 = 272B -> 2-way max bank aliasing, free);
// (2) K=256 GEMM (x half from global, agg half from LDS) + bias + relu +
// residual + layernorm.
__global__ __launch_bounds__(256) void fused_node_kernel(
    const float* __restrict__ x_drug, const float* __restrict__ x_prot,
    const int* __restrict__ rp, const int* __restrict__ pool,
    const bf16* __restrict__ y_dd, const bf16* __restrict__ y_pd,
    const bf16* __restrict__ y_dp,
    const bf16* __restrict__ Wdrug, const float* __restrict__ b_drug,
    const float* __restrict__ g_drug, const float* __restrict__ be_drug,
    const bf16* __restrict__ Wprot, const float* __restrict__ b_prot,
    const float* __restrict__ g_prot, const float* __restrict__ be_prot,
    float* __restrict__ out)
{
    __shared__ bf16 aggl[4][16][136];

    int blk = blockIdx.x;
    const float* x; const bf16* W; const float *b, *g, *be; float* o;
    const bf16 *y1, *y2; int M, rbase1, rbase2; bool two;
    if (blk < NBLK_D) {
        x = x_drug; W = Wdrug; b = b_drug; g = g_drug; be = be_drug;
        o = out; M = ND; rbase1 = 0; rbase2 = ND;
        y1 = y_dd; y2 = y_pd; two = true;
    } else {
        blk -= NBLK_D;
        x = x_prot; W = Wprot; b = b_prot; g = g_prot; be = be_prot;
        o = out + (long)ND * D; M = NP; rbase1 = 2 * ND; rbase2 = 0;
        y1 = y_dp; y2 = y_dp; two = false;
    }

    int lane = threadIdx.x & 63;
    int wave = threadIdx.x >> 6;
    int q = lane >> 4, c = lane & 15;
    int mb = blk * 64 + wave * 16;
    bf16* myagg = &aggl[wave][0][0];

    // ---- phase 1: gather 16 rows of agg into LDS (wave-local) ----
    for (int i = 0; i < 16; i++) {
        int gidx = min(mb + i, M - 1);
        int s1 = rp[rbase1 + gidx], e1 = rp[rbase1 + gidx + 1];
        float a[8] = {0.f, 0.f, 0.f, 0.f, 0.f, 0.f, 0.f, 0.f};
        for (int j = s1 + q; j < e1; j += 4) {
            int sid = pool[j];
            bf16x8 v = *(const bf16x8*)(y1 + (long)sid * D + c * 8);
#pragma unroll
            for (int k = 0; k < 8; k++) a[k] += (float)v[k];
        }
        float i1, i2;
        float bsum[8] = {0.f, 0.f, 0.f, 0.f, 0.f, 0.f, 0.f, 0.f};
        if (two) {
            int s2 = rp[rbase2 + gidx], e2 = rp[rbase2 + gidx + 1];
            for (int j = s2 + q; j < e2; j += 4) {
                int sid = pool[j];
                bf16x8 v = *(const bf16x8*)(y2 + (long)sid * D + c * 8);
#pragma unroll
                for (int k = 0; k < 8; k++) bsum[k] += (float)v[k];
            }
            i1 = 0.5f / (float)max(e1 - s1, 1);
            i2 = 0.5f / (float)max(e2 - s2, 1);
        } else {
            i1 = 1.0f / (float)max(e1 - s1, 1);
            i2 = 0.f;
        }
        bf16x8 ov;
#pragma unroll
        for (int k = 0; k < 8; k++) {
            float tt = a[k] * i1 + bsum[k] * i2;
            tt += __shfl_xor(tt, 16, 64);
            tt += __shfl_xor(tt, 32, 64);
            ov[k] = (bf16)tt;
        }
        if (q == 0)
            *(bf16x8*)(myagg + i * 136 + c * 8) = ov;
    }
    __syncthreads();   // safety; phases are wave-local but cheap to fence

    // ---- phase 2: GEMM(K=256) + bias + relu + residual + LN ----
    int rowA = min(mb + c, M - 1);
    f32x4 acc[8];
#pragma unroll
    for (int i = 0; i < 8; i++) acc[i] = 0;

    const float* xrow = x + (long)rowA * D;
#pragma unroll
    for (int kb = 0; kb < 8; kb++) {
        bf16x8 a;
        if (kb < 4) {
            int k = kb * 32 + q * 8;
            float4 f0 = *(const float4*)(xrow + k);
            float4 f1 = *(const float4*)(xrow + k + 4);
            a[0] = (bf16)f0.x; a[1] = (bf16)f0.y; a[2] = (bf16)f0.z; a[3] = (bf16)f0.w;
            a[4] = (bf16)f1.x; a[5] = (bf16)f1.y; a[6] = (bf16)f1.z; a[7] = (bf16)f1.w;
        } else {
            a = *(const bf16x8*)(myagg + c * 136 + (kb - 4) * 32 + q * 8);
        }
#pragma unroll
        for (int nt = 0; nt < 8; nt++) {
            int n = nt * 16 + c;
            bf16x8 bw = *(const bf16x8*)(W + n * (2 * D) + kb * 32 + q * 8);
            acc[nt] = __builtin_amdgcn_mfma_f32_16x16x32_bf16(a, bw, acc[nt], 0, 0, 0);
        }
    }

    float bv[8], gv[8], bev[8];
#pragma unroll
    for (int nt = 0; nt < 8; nt++) {
        int col = nt * 16 + c;
        bv[nt] = b[col]; gv[nt] = g[col]; bev[nt] = be[col];
    }
#pragma unroll
    for (int r = 0; r < 4; r++) {
        int row = mb + q * 4 + r;
        int rowc = min(row, M - 1);
        const float* xr = x + (long)rowc * D + c;
        float v[8];
        float sum = 0.f, sq = 0.f;
#pragma unroll
        for (int nt = 0; nt < 8; nt++) {
            float h = fmaxf(acc[nt][r] + bv[nt], 0.f);
            float t = h + xr[nt * 16];
            v[nt] = t; sum += t; sq += t * t;
        }
#pragma unroll
        for (int m = 1; m < 16; m <<= 1) {
            sum += __shfl_xor(sum, m, 64);
            sq  += __shfl_xor(sq,  m, 64);
        }
        float mu   = sum * (1.f / 128.f);
        float var  = sq  * (1.f / 128.f) - mu * mu;
        float rstd = rsqrtf(var + 1e-5f);
        if (row < M) {
            float* op = o + (long)row * D + c;
#pragma unroll
            for (int nt = 0; nt < 8; nt++)
                op[nt * 16] = (v[nt] - mu) * rstd * gv[nt] + bev[nt];
        }
    }
}

extern "C" void kernel_launch(void* const* d_in, const int* in_sizes, int n_in,
                              void* d_out, int out_size, void* d_ws, size_t ws_size,
                              hipStream_t stream)
{
    const float* x_drug  = (const float*)d_in[0];
    const float* x_prot  = (const float*)d_in[1];
    const float* Wagg_dd = (const float*)d_in[2];
    const float* Wagg_dp = (const float*)d_in[3];
    const float* Wagg_pd = (const float*)d_in[4];
    const float* W_drug  = (const float*)d_in[5];
    const float* b_drug  = (const float*)d_in[6];
    const float* W_prot  = (const float*)d_in[7];
    const float* b_prot  = (const float*)d_in[8];
    const float* g_drug  = (const float*)d_in[9];
    const float* be_drug = (const float*)d_in[10];
    const float* g_prot  = (const float*)d_in[11];
    const float* be_prot = (const float*)d_in[12];
    const int* dd_src = (const int*)d_in[13];
    const int* dd_dst = (const int*)d_in[14];
    const int* dp_src = (const int*)d_in[15];
    const int* dp_dst = (const int*)d_in[16];
    const int* pd_src = (const int*)d_in[17];
    const int* pd_dst = (const int*)d_in[18];

    char* ws = (char*)d_ws;
    bf16* Wdd   = (bf16*)(ws + OFF_WDD);
    bf16* Wdp   = (bf16*)(ws + OFF_WDP);
    bf16* Wpd   = (bf16*)(ws + OFF_WPD);
    bf16* Wdrug = (bf16*)(ws + OFF_WDRUG);
    bf16* Wprot = (bf16*)(ws + OFF_WPROT);
    bf16* y_dd  = (bf16*)(ws + OFF_YDD);
    bf16* y_dp  = (bf16*)(ws + OFF_YDP);
    bf16* y_pd  = (bf16*)(ws + OFF_YPD);
    int* bcnt   = (int*)(ws + OFF_BCNT);
    int* gcur   = (int*)(ws + OFF_GCUR);
    int* rp     = (int*)(ws + OFF_RP);
    int2* pairs = (int2*)(ws + OFF_PAIRS);
    int* pool   = (int*)(ws + OFF_POOL);
    float* out  = (float*)d_out;

    // 1) weights->bf16 + zero bcnt/gcur
    prep_kernel<<<dim3(128, 6), 256, 0, stream>>>(
        Wagg_dd, Wagg_dp, Wagg_pd, W_drug, W_prot,
        Wdd, Wdp, Wpd, Wdrug, Wprot, bcnt);

    // 2) per-node transforms + coarse histogram (independent block ranges)
    transform_hist_kernel<<<NBLK_D + NBLK_P + NBLKA, 256, 0, stream>>>(
        x_drug, x_prot, Wdd, Wdp, Wpd, y_dd, y_dp, y_pd,
        dd_dst, pd_dst, dp_dst, bcnt);

    // 3) coarse binning (scan folded in)
    binA_kernel<<<NBLKA, 256, 0, stream>>>(
        dd_src, dd_dst, pd_src, pd_dst, dp_src, dp_dst, bcnt, gcur, pairs);

    // 4) per-bucket counting sort -> pool + rp
    sortB_kernel<<<NBC, 256, 0, stream>>>(bcnt, pairs, pool, rp);

    // 5) fused gather + node update
    fused_node_kernel<<<NBLK_D + NBLK_P, 256, 0, stream>>>(
        x_drug, x_prot, rp, pool, y_dd, y_pd, y_dp,
        Wdrug, b_drug, g_drug, be_drug,
        Wprot, b_prot, g_prot, be_prot, out);
}